// Round 2
// baseline (133.401 us; speedup 1.0000x reference)
//
#include <hip/hip_runtime.h>
#include <math.h>

// Problem geometry (fixed by setup_inputs)
#define NT    32
#define NA    64
#define NB    64
#define NGEO  128
#define NELEM (NT * NA * NB * NGEO)   // 16777216 = 2^24

// Per-point emission, fully branch-free.
//
// Accuracy contract (absmax threshold = 2% of sigmoid(-20)):
//  * MASK decisions (t_rot>=0, 2<=r<=10, |z|<=4) must bit-match the numpy
//    f32 reference -> __f*_rn intrinsics (blocks -ffp-contract=fast) +
//    correctly-rounded sqrtf. Verified absmax==0.0 in R1 with this chain.
//  * Everything downstream (rotation, interp weights, sigmoid) is a
//    CONTINUOUS path: since the interp weights come in complementary pairs,
//    coordinate error eps perturbs the result only by O(eps) relative.
//    Hardware v_sin/v_cos/v_exp/v_rcp (~1e-6 rel) give ~1e-4 relative
//    emission error, ~100x under the 2% threshold.
__device__ __forceinline__ float emission_point(
    float x, float y, float z, float Om, float tg,
    float tM, float tinj, const float* __restrict__ grid)
{
    // t_rot = (t_M - t_geos) - t_injection   (exact order match, no contract)
    float t_rot = __fsub_rn(__fsub_rn(tM, tg), tinj);

    // r = sqrt((x*x + y*y) + z*z), left-assoc, no fma; sqrtf correctly rounded
    float r2 = __fadd_rn(__fadd_rn(__fmul_rn(x, x), __fmul_rn(y, y)),
                         __fmul_rn(z, z));
    float r = sqrtf(r2);

    bool alive = (t_rot >= 0.0f) & (r >= 2.0f) & (r <= 10.0f) &
                 (fabsf(z) <= 4.0f);

    // warp-back rotation about z: hardware sin/cos (input in revolutions)
    float theta = -Om * t_rot;                       // |theta| <= ~18.3 rad
    float rev = theta * 0.15915494309189535f;        // /(2*pi)
    rev = rev - floorf(rev);                         // [0,1) for v_sin/v_cos
    float s = __builtin_amdgcn_sinf(rev);
    float c = __builtin_amdgcn_cosf(rev);
    float xw = x * c - y * s;
    float yw = x * s + y * c;

    // grid index space: (v + 10) / 20 * 63.  Clamp into [0, 63) so indices
    // are always in-bounds (dead lanes included); for live lanes the clamp
    // only acts within ~4e-6 of the domain edge (rotation rounding), which
    // perturbs the weight product by <1e-5 -> negligible.
    float fx = (xw + 10.0f) * 3.15f;
    float fy = (yw + 10.0f) * 3.15f;
    float fz = (z  + 10.0f) * 3.15f;
    fx = fminf(fmaxf(fx, 0.0f), 62.999996f);
    fy = fminf(fmaxf(fy, 0.0f), 62.999996f);
    fz = fminf(fmaxf(fz, 0.0f), 62.999996f);

    int ix0 = (int)fx, iy0 = (int)fy, iz0 = (int)fz;   // == floor (fx>=0)
    float wx1 = fx - (float)ix0, wy1 = fy - (float)iy0, wz1 = fz - (float)iz0;
    float wx0 = 1.0f - wx1, wy0 = 1.0f - wy1, wz0 = 1.0f - wz1;

    // dead lanes gather grid[0] (wave-broadcast, L1 hit) instead of random
    // voxels -> no wasted L2 traffic, but no branch either (full ILP).
    int bidx = ix0 * 4096 + iy0 * 64 + iz0;
    bidx = alive ? bidx : 0;
    const float* g = grid + bidx;

    float v000 = g[0],    v001 = g[1];
    float v010 = g[64],   v011 = g[65];
    float v100 = g[4096], v101 = g[4097];
    float v110 = g[4160], v111 = g[4161];

    float c00 = v000 * wz0 + v001 * wz1;
    float c01 = v010 * wz0 + v011 * wz1;
    float c10 = v100 * wz0 + v101 * wz1;
    float c11 = v110 * wz0 + v111 * wz1;
    float c0  = c00 * wy0 + c01 * wy1;
    float c1  = c10 * wy0 + c11 * wy1;
    float net = (c0 * wx0 + c1 * wx1);

    // sigmoid(net - 10) = 1 / (1 + e^(10-net)); hardware exp2 + rcp
    float E = __expf(10.0f - net);
    float sig = __builtin_amdgcn_rcpf(1.0f + E);
    return alive ? sig : 0.0f;
}

__global__ __launch_bounds__(256) void grid_predictor_kernel(
    const float* __restrict__ t_frames,
    const float* __restrict__ coords,   // 3 contiguous planes of NELEM
    const float* __restrict__ Omega,
    const float* __restrict__ t_geos,
    const float* __restrict__ t_inj,
    const float* __restrict__ t_start,
    const float* __restrict__ grid,
    float* __restrict__ out)
{
    int i = (blockIdx.x * 256 + threadIdx.x) * 4;      // < 2^24, int is fine

    // 1024 elems per block, 2^19 per t-plane -> t uniform per block (scalar)
    int t = blockIdx.x >> 9;
    float tM   = __fsub_rn(t_frames[t], t_start[0]);
    float tinj = t_inj[0];

    float4 x4 = *(const float4*)(coords + i);
    float4 y4 = *(const float4*)(coords + NELEM + i);
    float4 z4 = *(const float4*)(coords + 2 * NELEM + i);
    float4 o4 = *(const float4*)(Omega + i);
    float4 g4 = *(const float4*)(t_geos + i);

    float4 r;
    r.x = emission_point(x4.x, y4.x, z4.x, o4.x, g4.x, tM, tinj, grid);
    r.y = emission_point(x4.y, y4.y, z4.y, o4.y, g4.y, tM, tinj, grid);
    r.z = emission_point(x4.z, y4.z, z4.z, o4.z, g4.z, tM, tinj, grid);
    r.w = emission_point(x4.w, y4.w, z4.w, o4.w, g4.w, tM, tinj, grid);

    *(float4*)(out + i) = r;
}

extern "C" void kernel_launch(void* const* d_in, const int* in_sizes, int n_in,
                              void* d_out, int out_size, void* d_ws, size_t ws_size,
                              hipStream_t stream) {
    const float* t_frames = (const float*)d_in[0];
    const float* coords   = (const float*)d_in[1];
    const float* Omega    = (const float*)d_in[2];
    const float* t_geos   = (const float*)d_in[3];
    const float* t_inj    = (const float*)d_in[4];
    const float* t_start  = (const float*)d_in[5];
    const float* grid     = (const float*)d_in[6];
    float* out = (float*)d_out;

    const int threads = 256;
    const int blocks = NELEM / 4 / threads;            // 16384
    grid_predictor_kernel<<<blocks, threads, 0, stream>>>(
        t_frames, coords, Omega, t_geos, t_inj, t_start, grid, out);
}

// Round 4
// 113.956 us; speedup vs baseline: 1.1706x; 1.1706x over previous
//
#include <hip/hip_runtime.h>
#include <math.h>

// Problem geometry (fixed by setup_inputs)
#define NT    32
#define NA    64
#define NB    64
#define NGEO  128
#define NELEM (NT * NA * NB * NGEO)   // 16777216 = 2^24
#define GR    64
#define NQ    (GR * GR * GR)          // 262144 quad cells
#define QBYTES ((size_t)NQ * 16)      // 4 MiB

// clang ext-vector float4: accepted by __builtin_nontemporal_load/store
// (HIP_vector_type float4 is NOT). Same layout, same dwordx4 codegen.
typedef float vf4 __attribute__((ext_vector_type(4)));

// ---------------------------------------------------------------------------
// Pre-pass: pack each voxel's (y,z) 2x2 face into one aligned float4 so the
// main kernel's 8 divergent 4B gathers become 2 divergent 16B gathers.
// Q[x][y][z] = { g(x,y,z), g(x,y,z+1), g(x,y+1,z), g(x,y+1,z+1) }
// (y=63 / z=63 entries are never read with nonzero weight; clamp for safety)
__global__ __launch_bounds__(256) void build_quads(
    const float* __restrict__ g, vf4* __restrict__ q)
{
    int idx = blockIdx.x * 256 + threadIdx.x;          // 0 .. NQ-1
    int z = idx & 63, y = (idx >> 6) & 63, x = idx >> 12;
    int zc = min(z + 1, 63), yc = min(y + 1, 63);
    const float* gx = g + x * 4096;
    vf4 v;
    v.x = gx[y  * 64 + z];  v.y = gx[y  * 64 + zc];
    v.z = gx[yc * 64 + z];  v.w = gx[yc * 64 + zc];
    q[idx] = v;
}

// ---------------------------------------------------------------------------
// Per-point emission, fully branch-free.
//
// Accuracy contract (absmax threshold = 2% of max output):
//  * MASK decisions (t_rot>=0, 2<=r<=10, |z|<=4) bit-match the numpy f32
//    reference -> __f*_rn intrinsics (no fp-contract) + rounded sqrtf.
//    Verified absmax==0.0 in R1/R2.
//  * Value path (rotation, weights, sigmoid) is continuous; hardware
//    v_sin/v_cos/v_exp/v_rcp give ~1e-5 relative error, ~1000x under
//    threshold. Quad table holds the exact same f32 values as `grid`,
//    so interpolation arithmetic is bit-identical to R2.
template <bool QUAD>
__device__ __forceinline__ float emission_point(
    float x, float y, float z, float Om, float tg,
    float tM, float tinj, const void* __restrict__ tbl)
{
    float t_rot = __fsub_rn(__fsub_rn(tM, tg), tinj);
    float r2 = __fadd_rn(__fadd_rn(__fmul_rn(x, x), __fmul_rn(y, y)),
                         __fmul_rn(z, z));
    float r = sqrtf(r2);

    bool alive = (t_rot >= 0.0f) & (r >= 2.0f) & (r <= 10.0f) &
                 (fabsf(z) <= 4.0f);

    // warp-back rotation about z (hardware sin/cos take revolutions)
    float theta = -Om * t_rot;
    float rev = theta * 0.15915494309189535f;
    rev = rev - floorf(rev);
    float s = __builtin_amdgcn_sinf(rev);
    float c = __builtin_amdgcn_cosf(rev);
    float xw = x * c - y * s;
    float yw = x * s + y * c;

    // grid index space: (v + 10) / 20 * 63, clamped into [0, 63)
    float fx = (xw + 10.0f) * 3.15f;
    float fy = (yw + 10.0f) * 3.15f;
    float fz = (z  + 10.0f) * 3.15f;
    fx = fminf(fmaxf(fx, 0.0f), 62.999996f);
    fy = fminf(fmaxf(fy, 0.0f), 62.999996f);
    fz = fminf(fmaxf(fz, 0.0f), 62.999996f);

    int ix0 = (int)fx, iy0 = (int)fy, iz0 = (int)fz;
    float wx1 = fx - (float)ix0, wy1 = fy - (float)iy0, wz1 = fz - (float)iz0;
    float wx0 = 1.0f - wx1, wy0 = 1.0f - wy1, wz0 = 1.0f - wz1;

    int bidx = ix0 * 4096 + iy0 * 64 + iz0;
    bidx = alive ? bidx : 0;         // dead lanes: broadcast line, no branch

    float v000, v001, v010, v011, v100, v101, v110, v111;
    if (QUAD) {
        const vf4* q = (const vf4*)tbl;
        vf4 q0 = q[bidx];             // 16B aligned: 1 line per lane
        vf4 q1 = q[bidx + 4096];
        v000 = q0.x; v001 = q0.y; v010 = q0.z; v011 = q0.w;
        v100 = q1.x; v101 = q1.y; v110 = q1.z; v111 = q1.w;
    } else {
        const float* g = (const float*)tbl + bidx;
        v000 = g[0];    v001 = g[1];
        v010 = g[64];   v011 = g[65];
        v100 = g[4096]; v101 = g[4097];
        v110 = g[4160]; v111 = g[4161];
    }

    float c00 = v000 * wz0 + v001 * wz1;
    float c01 = v010 * wz0 + v011 * wz1;
    float c10 = v100 * wz0 + v101 * wz1;
    float c11 = v110 * wz0 + v111 * wz1;
    float c0  = c00 * wy0 + c01 * wy1;
    float c1  = c10 * wy0 + c11 * wy1;
    float net = c0 * wx0 + c1 * wx1;

    float E = __expf(10.0f - net);                 // sigmoid(net - 10)
    float sig = __builtin_amdgcn_rcpf(1.0f + E);
    return alive ? sig : 0.0f;
}

template <bool QUAD>
__global__ __launch_bounds__(256) void grid_predictor_kernel(
    const float* __restrict__ t_frames,
    const float* __restrict__ coords,
    const float* __restrict__ Omega,
    const float* __restrict__ t_geos,
    const float* __restrict__ t_inj,
    const float* __restrict__ t_start,
    const void*  __restrict__ tbl,     // quad table (QUAD) or raw grid
    float* __restrict__ out)
{
    int i = (blockIdx.x * 256 + threadIdx.x) * 4;

    int t = blockIdx.x >> 9;                       // t uniform per block
    float tM   = __fsub_rn(t_frames[t], t_start[0]);
    float tinj = t_inj[0];

    // Non-temporal: the 320MB pass-through stream must not evict the 4MB
    // quad table from per-XCD L2.
    vf4 x4 = __builtin_nontemporal_load((const vf4*)(coords + i));
    vf4 y4 = __builtin_nontemporal_load((const vf4*)(coords + NELEM + i));
    vf4 z4 = __builtin_nontemporal_load((const vf4*)(coords + 2 * NELEM + i));
    vf4 o4 = __builtin_nontemporal_load((const vf4*)(Omega + i));
    vf4 g4 = __builtin_nontemporal_load((const vf4*)(t_geos + i));

    vf4 r;
    r.x = emission_point<QUAD>(x4.x, y4.x, z4.x, o4.x, g4.x, tM, tinj, tbl);
    r.y = emission_point<QUAD>(x4.y, y4.y, z4.y, o4.y, g4.y, tM, tinj, tbl);
    r.z = emission_point<QUAD>(x4.z, y4.z, z4.z, o4.z, g4.z, tM, tinj, tbl);
    r.w = emission_point<QUAD>(x4.w, y4.w, z4.w, o4.w, g4.w, tM, tinj, tbl);

    __builtin_nontemporal_store(r, (vf4*)(out + i));
}

extern "C" void kernel_launch(void* const* d_in, const int* in_sizes, int n_in,
                              void* d_out, int out_size, void* d_ws, size_t ws_size,
                              hipStream_t stream) {
    const float* t_frames = (const float*)d_in[0];
    const float* coords   = (const float*)d_in[1];
    const float* Omega    = (const float*)d_in[2];
    const float* t_geos   = (const float*)d_in[3];
    const float* t_inj    = (const float*)d_in[4];
    const float* t_start  = (const float*)d_in[5];
    const float* grid     = (const float*)d_in[6];
    float* out = (float*)d_out;

    const int threads = 256;
    const int blocks = NELEM / 4 / threads;        // 16384

    if (ws_size >= QBYTES) {
        vf4* q = (vf4*)d_ws;
        build_quads<<<NQ / 256, 256, 0, stream>>>(grid, q);
        grid_predictor_kernel<true><<<blocks, threads, 0, stream>>>(
            t_frames, coords, Omega, t_geos, t_inj, t_start, q, out);
    } else {
        grid_predictor_kernel<false><<<blocks, threads, 0, stream>>>(
            t_frames, coords, Omega, t_geos, t_inj, t_start, grid, out);
    }
}